// Round 2
// baseline (1121.398 us; speedup 1.0000x reference)
//
#include <hip/hip_runtime.h>
#include <hip/hip_cooperative_groups.h>

namespace cg = cooperative_groups;

// ---------------------------------------------------------------------------
// GCN fraud detector — R12: cooperative mega-fusion.
// R11 post-mortem: removing graph-build global atomics = NEUTRAL (436 vs 435).
// Per-phase roofline sums to ~280us vs 435 measured -> ~150us is dispatch
// overhead across 17 serialized launches + sub-top5 kernels. Every kernel
// boundary is a grid-wide dep, so fuse via hipLaunchCooperativeKernel +
// grid.sync():
//   K1 = {wfrag, count, scan, place, part2, GEMM0}   (coop, <=1024 blocks)
//   K2 = {stats1_0, stats2_0 || W-stage, GEMM1}      (coop)
//   K3 = {stats1_1, stats2_1 || W-stage, GEMM2}      (coop)
//   K4 = {stats1_2, stats2_2 || head-stage, head}    (coop)
// agg128/agg64 stay plain launches (they need ~70% occupancy; coop grid is
// capped at 4 blocks/CU). 17 dispatches -> 7.
// Agg: wave/node, ushort2 row loads, 16 gathers in flight. ~59us line-fill
// floor (L2-miss path ~3.2TB/s on 192MB HBM re-fetch; bytes are minimal for
// bf16). UNCHANGED.
// ---------------------------------------------------------------------------

typedef __attribute__((ext_vector_type(8))) short short8;
typedef __attribute__((ext_vector_type(4))) float f32x4;

#define BIN_SHIFT 7
#define BIN_NODES 128
#define CAPB 4096
#define CAP 64

__device__ __forceinline__ float b2f(unsigned short u) {
    return __uint_as_float(((unsigned)u) << 16);
}
__device__ __forceinline__ unsigned short f2bf(float f) {
    unsigned u = __float_as_uint(f);
    return (unsigned short)((u + 0x7fff + ((u >> 16) & 1)) >> 16);
}

__device__ __forceinline__ void load8(const float* p, float4& lo, float4& hi) {
    lo = *(const float4*)p;
    hi = *(const float4*)(p + 4);
}
__device__ __forceinline__ void load8(const unsigned short* p, float4& lo, float4& hi) {
    int4 q = *(const int4*)p;
    lo = make_float4(__uint_as_float((unsigned)q.x << 16),
                     __uint_as_float((unsigned)q.x & 0xffff0000u),
                     __uint_as_float((unsigned)q.y << 16),
                     __uint_as_float((unsigned)q.y & 0xffff0000u));
    hi = make_float4(__uint_as_float((unsigned)q.z << 16),
                     __uint_as_float((unsigned)q.z & 0xffff0000u),
                     __uint_as_float((unsigned)q.w << 16),
                     __uint_as_float((unsigned)q.w & 0xffff0000u));
}

// ---------------- phases (device functions; barriers are per-block) --------

__device__ void wfrag_phase(const float* __restrict__ w0, const float* __restrict__ w1,
                            const float* __restrict__ w2, unsigned short* __restrict__ wf) {
    int tg = blockIdx.x * 256 + threadIdx.x;
    if (tg >= 40960) return;
    const float* w;
    int idx, C;
    if (tg < 16384) { w = w0; idx = tg; C = 128; }
    else if (tg < 32768) { w = w1; idx = tg - 16384; C = 128; }
    else { w = w2; idx = tg - 32768; C = 64; }
    int j = idx & 7;
    int lane = (idx >> 3) & 63;
    int q = (idx >> 9) & 3;
    int n_tile = idx >> 11;
    int k = q * 32 + (lane >> 4) * 8 + j;
    int n = n_tile * 16 + (lane & 15);
    wf[tg] = f2bf(w[k * C + n]);
}

__device__ void count_phase(const int* __restrict__ eidx, int E, int CB, int chunk,
                            int nbins, int* __restrict__ cntG, int* cntS) {
    int tid = threadIdx.x;
    if (blockIdx.x >= CB) return;
    for (int b = tid; b < 1024; b += 256) cntS[b] = 0;
    __syncthreads();
    int e0 = blockIdx.x * chunk;
    int e1 = min(e0 + chunk, E);
    for (int e = e0 + tid; e < e1; e += 256)
        atomicAdd(&cntS[eidx[E + e] >> BIN_SHIFT], 1);
    __syncthreads();
    for (int b = tid; b < nbins; b += 256) cntG[b * CB + blockIdx.x] = cntS[b];
}

__device__ void scan_phase(int nbins, int CB, int* __restrict__ cntG,
                           int* __restrict__ bin_fill, int* sh) {
    int t = threadIdx.x;
    for (int b = blockIdx.x; b < nbins; b += gridDim.x) {
        int v = (t < CB) ? cntG[b * CB + t] : 0;
        sh[t] = v;
        __syncthreads();
        for (int d = 1; d < 256; d <<= 1) {
            int u = (t >= d) ? sh[t - d] : 0;
            __syncthreads();
            sh[t] += u;
            __syncthreads();
        }
        if (t < CB) cntG[b * CB + t] = sh[t] - v;  // exclusive base, in place
        if (t == 255) bin_fill[b] = sh[255];
        __syncthreads();
    }
}

__device__ void place_phase(const int* __restrict__ eidx, int E, int CB, int chunk,
                            int nbins, const int* __restrict__ baseG,
                            int* __restrict__ binned, int* cntS, int* baseS) {
    int tid = threadIdx.x;
    if (blockIdx.x >= CB) return;
    for (int b = tid; b < nbins; b += 256) {
        baseS[b] = baseG[b * CB + blockIdx.x];
        cntS[b] = 0;
    }
    __syncthreads();
    int e0 = blockIdx.x * chunk;
    int e1 = min(e0 + chunk, E);
    for (int e = e0 + tid; e < e1; e += 256) {
        int d = eidx[E + e];
        int s = eidx[e];
        int b = d >> BIN_SHIFT;
        int p = baseS[b] + atomicAdd(&cntS[b], 1);
        if (p < CAPB) binned[b * CAPB + p] = (s << BIN_SHIFT) | (d & (BIN_NODES - 1));
    }
}

__device__ void part2_phase(const int* __restrict__ bin_fill, const int* __restrict__ binned,
                            int N, int* __restrict__ fill, float* __restrict__ dis,
                            int* __restrict__ stg, int* lfill) {
    int nb = (N + BIN_NODES - 1) >> BIN_SHIFT;
    int tid = threadIdx.x;
    for (int b = blockIdx.x; b < nb; b += gridDim.x) {
        if (tid < BIN_NODES) lfill[tid] = 0;
        __syncthreads();
        int cnt = min(bin_fill[b], CAPB);
        const int* seg = binned + b * CAPB;
        for (int i = tid; i < cnt; i += 256) {
            int v = seg[i];
            int dl = v & (BIN_NODES - 1);
            int pp = atomicAdd(&lfill[dl], 1);
            int node = (b << BIN_SHIFT) + dl;
            if (pp < CAP) stg[(node << 6) + pp] = v >> BIN_SHIFT;
        }
        __syncthreads();
        if (tid < BIN_NODES) {
            int node = (b << BIN_SHIFT) + tid;
            if (node < N) {
                int c = lfill[tid];
                fill[node] = c;
                dis[node] = rsqrtf((float)c + 1.0f);
            }
        }
        __syncthreads();
    }
}

template <int C>
__device__ void stage_w_phase(const unsigned short* __restrict__ wfp, short8* ws) {
    constexpr int WFRAGS = (C / 16) * 4 * 64;
    for (int i = threadIdx.x; i < WFRAGS; i += 256) ws[i] = ((const short8*)wfp)[i];
}

// GEMM tiles: out[N x C](bf16) = dis_row * (relu(xin*scale+shift) @ W), W in ws.
template <int C, typename InT>
__device__ void gemm_tiles_phase(const InT* __restrict__ xin,
                                 const float* __restrict__ scale,
                                 const float* __restrict__ shift,
                                 const float* __restrict__ dis,
                                 unsigned short* __restrict__ out, int N,
                                 const short8* ws) {
    constexpr int NT = C / 16;
    int tid = threadIdx.x;
    int lane = tid & 63;
    int wave = tid >> 6;
    int r15 = lane & 15, r4 = lane >> 4;
    int ntiles = (N + 63) / 64;
    for (int bx = blockIdx.x; bx < ntiles; bx += gridDim.x) {
        int m0 = bx * 64 + wave * 16;
        f32x4 acc[NT];
#pragma unroll
        for (int t = 0; t < NT; t++) acc[t] = (f32x4){0.f, 0.f, 0.f, 0.f};
        int row0c = min(m0 + r15, N - 1);
#pragma unroll
        for (int q = 0; q < 4; q++) {
            int kb = q * 32 + r4 * 8;
            float4 a0l, a0h;
            load8(xin + (size_t)row0c * 128 + kb, a0l, a0h);
            if (scale) {
                float4 scl = *(const float4*)&scale[kb];
                float4 sch = *(const float4*)&scale[kb + 4];
                float4 shl = *(const float4*)&shift[kb];
                float4 shh = *(const float4*)&shift[kb + 4];
                a0l.x = fmaxf(a0l.x * scl.x + shl.x, 0.f);
                a0l.y = fmaxf(a0l.y * scl.y + shl.y, 0.f);
                a0l.z = fmaxf(a0l.z * scl.z + shl.z, 0.f);
                a0l.w = fmaxf(a0l.w * scl.w + shl.w, 0.f);
                a0h.x = fmaxf(a0h.x * sch.x + shh.x, 0.f);
                a0h.y = fmaxf(a0h.y * sch.y + shh.y, 0.f);
                a0h.z = fmaxf(a0h.z * sch.z + shh.z, 0.f);
                a0h.w = fmaxf(a0h.w * sch.w + shh.w, 0.f);
            }
            short8 a0;
            a0[0] = (short)f2bf(a0l.x); a0[1] = (short)f2bf(a0l.y);
            a0[2] = (short)f2bf(a0l.z); a0[3] = (short)f2bf(a0l.w);
            a0[4] = (short)f2bf(a0h.x); a0[5] = (short)f2bf(a0h.y);
            a0[6] = (short)f2bf(a0h.z); a0[7] = (short)f2bf(a0h.w);
#pragma unroll
            for (int nt = 0; nt < NT; nt++) {
                short8 b = ws[(nt * 4 + q) * 64 + lane];
                acc[nt] = __builtin_amdgcn_mfma_f32_16x16x32_bf16(a0, b, acc[nt], 0, 0, 0);
            }
        }
        float d0r[4];
#pragma unroll
        for (int r = 0; r < 4; r++) {
            int rowa = m0 + r4 * 4 + r;
            d0r[r] = (rowa < N) ? dis[rowa] : 0.f;
        }
#pragma unroll
        for (int nt = 0; nt < NT; nt++) {
            int col = nt * 16 + r15;
#pragma unroll
            for (int r = 0; r < 4; r++) {
                int rowa = m0 + r4 * 4 + r;
                if (rowa < N) out[(size_t)rowa * C + col] = f2bf(acc[nt][r] * d0r[r]);
            }
        }
    }
}

template <int C>
__device__ void stats1_phase(const unsigned short* __restrict__ h, int N,
                             float* __restrict__ partials, float* red) {
    constexpr int CG = C / 4;
    constexpr int RG = 256 / CG;
    int t = threadIdx.x;
    int cgi = t % CG;
    int rg = t / CG;
    float s[4] = {0.f, 0.f, 0.f, 0.f}, q[4] = {0.f, 0.f, 0.f, 0.f};
    for (int n = blockIdx.x * RG + rg; n < N; n += gridDim.x * RG) {
        ushort4 v = *(const ushort4*)&h[(size_t)n * C + cgi * 4];
        float f0 = b2f(v.x), f1 = b2f(v.y), f2 = b2f(v.z), f3 = b2f(v.w);
        s[0] += f0; s[1] += f1; s[2] += f2; s[3] += f3;
        q[0] += f0 * f0; q[1] += f1 * f1; q[2] += f2 * f2; q[3] += f3 * f3;
    }
#pragma unroll
    for (int k = 0; k < 4; k++) {
        red[(rg * CG + cgi) * 8 + k] = s[k];
        red[(rg * CG + cgi) * 8 + 4 + k] = q[k];
    }
    __syncthreads();
    if (rg == 0) {
#pragma unroll
        for (int w = 1; w < RG; w++)
#pragma unroll
            for (int k = 0; k < 4; k++) {
                s[k] += red[(w * CG + cgi) * 8 + k];
                q[k] += red[(w * CG + cgi) * 8 + 4 + k];
            }
        float* pb = partials + (size_t)blockIdx.x * 2 * C;
#pragma unroll
        for (int k = 0; k < 4; k++) {
            pb[cgi * 4 + k] = s[k];
            pb[C + cgi * 4 + k] = q[k];
        }
    }
    __syncthreads();
}

template <int C>
__device__ void stats2_phase(const float* __restrict__ partials, const float* __restrict__ g,
                             const float* __restrict__ be, int N,
                             float* __restrict__ scale, float* __restrict__ shift) {
    __shared__ float rs[256], rq[256];
    int t = threadIdx.x;
    int nparts = gridDim.x;
    for (int c = blockIdx.x; c < C; c += gridDim.x) {
        float s = 0.f, q = 0.f;
        for (int b = t; b < nparts; b += 256) {
            const float* pb = partials + (size_t)b * 2 * C;
            s += pb[c];
            q += pb[C + c];
        }
        rs[t] = s;
        rq[t] = q;
        __syncthreads();
        for (int d = 128; d > 0; d >>= 1) {
            if (t < d) {
                rs[t] += rs[t + d];
                rq[t] += rq[t + d];
            }
            __syncthreads();
        }
        if (t == 0) {
            float inv_n = 1.0f / (float)N;
            float mean = rs[0] * inv_n;
            float var = rq[0] * inv_n - mean * mean;
            var = var > 0.f ? var : 0.f;
            float sc = g[c] * rsqrtf(var + 1e-5f);
            scale[c] = sc;
            shift[c] = be[c] - mean * sc;
        }
        __syncthreads();
    }
}

__device__ void head_stage(const float* __restrict__ wc1, const float* __restrict__ bc1,
                           const float* __restrict__ wc2, const float* __restrict__ bc2,
                           float* w1s, float* b1s, float* w2s, float* b2s) {
    int tid = threadIdx.x;
    for (int i = tid; i < 64 * 32; i += 256) w1s[i] = wc1[i];
    if (tid < 32) { b1s[tid] = bc1[tid]; w2s[tid] = wc2[tid]; }
    if (tid == 0) b2s[0] = bc2[0];
}

__device__ void head_compute(const unsigned short* __restrict__ h,
                             const float* __restrict__ scale, const float* __restrict__ shift,
                             float* __restrict__ out, int N, const float* w1s,
                             const float* b1s, const float* w2s, const float* b2s,
                             float* s2s, float* sh2v) {
    int tid = threadIdx.x;
    if (tid < 64) { s2s[tid] = scale[tid]; sh2v[tid] = shift[tid]; }
    __syncthreads();
    for (int bx = blockIdx.x; bx * 256 < N; bx += gridDim.x) {
        int n = bx * 256 + tid;
        if (n < N) {
            float v[64];
#pragma unroll
            for (int k = 0; k < 64; k++) {
                float xv = b2f(h[(size_t)n * 64 + k]) * s2s[k] + sh2v[k];
                v[k] = xv > 0.f ? xv : 0.f;
            }
            float o = b2s[0];
#pragma unroll 2
            for (int j = 0; j < 32; j++) {
                float t = b1s[j];
#pragma unroll
                for (int k = 0; k < 64; k++) t += v[k] * w1s[k * 32 + j];
                t = t > 0.f ? t : 0.f;
                o += t * w2s[j];
            }
            out[n] = o;
        }
    }
}

// ---------------- fused cooperative kernels --------------------------------

__global__ __launch_bounds__(256, 4) void fusedA_kernel(
    const int* eidx, int E, int nbins, int CB, int chunk, int* cntG, int* bin_fill,
    int* binned, int N, int* fill, float* dis, int* stg, const float* w0,
    const float* w1, const float* w2, unsigned short* wf, const float* x,
    unsigned short* hA) {
    __shared__ __align__(16) int ibuf[8192];  // 32KB, phase-reused
    __shared__ int lfill[BIN_NODES];
    cg::grid_group grid = cg::this_grid();
    wfrag_phase(w0, w1, w2, wf);
    count_phase(eidx, E, CB, chunk, nbins, cntG, ibuf);
    grid.sync();
    scan_phase(nbins, CB, cntG, bin_fill, ibuf);
    grid.sync();
    place_phase(eidx, E, CB, chunk, nbins, cntG, binned, ibuf, ibuf + 1024);
    grid.sync();
    part2_phase(bin_fill, binned, N, fill, dis, stg, lfill);
    stage_w_phase<128>(wf, (short8*)ibuf);  // overlaps part2 (ibuf free here)
    grid.sync();
    gemm_tiles_phase<128, float>(x, (const float*)nullptr, (const float*)nullptr,
                                 dis, hA, N, (const short8*)ibuf);
}

template <int CS, int CO>
__global__ __launch_bounds__(256, 4) void fusedB_kernel(
    const unsigned short* hin, const float* g, const float* be, float* partials,
    float* scale, float* shift, const unsigned short* wfp, const float* dis,
    unsigned short* hout, int N) {
    __shared__ __align__(16) float fbuf[8192];  // 32KB: stats red then W frags
    cg::grid_group grid = cg::this_grid();
    stats1_phase<CS>(hin, N, partials, fbuf);
    grid.sync();
    stats2_phase<CS>(partials, g, be, N, scale, shift);  // blocks >= CS skip
    stage_w_phase<CO>(wfp, (short8*)fbuf);               // all blocks, overlaps
    grid.sync();
    gemm_tiles_phase<CO, unsigned short>(hin, scale, shift, dis, hout, N,
                                         (const short8*)fbuf);
}

__global__ __launch_bounds__(256, 4) void fusedC_kernel(
    const unsigned short* hin, const float* g, const float* be, float* partials,
    float* scale, float* shift, const float* wc1, const float* bc1, const float* wc2,
    const float* bc2, float* out, int N) {
    __shared__ __align__(16) float fbuf[2048];  // 8KB: stats red == head w1s
    __shared__ float b1s[32], w2s[32], s2s[64], sh2v[64], b2sv[1];
    cg::grid_group grid = cg::this_grid();
    stats1_phase<64>(hin, N, partials, fbuf);
    grid.sync();
    stats2_phase<64>(partials, g, be, N, scale, shift);
    head_stage(wc1, bc1, wc2, bc2, fbuf, b1s, w2s, b2sv);  // overlaps stats2
    grid.sync();
    head_compute(hin, scale, shift, out, N, fbuf, b1s, w2s, b2sv, s2s, sh2v);
}

// ---------------- agg kernels (plain launches, unchanged) ------------------

__global__ __launch_bounds__(256) void agg128_kernel(
    const unsigned short* __restrict__ h, const int* __restrict__ fill,
    const int* __restrict__ stage, const float* __restrict__ dis,
    unsigned short* __restrict__ out, int N) {
    int lane = threadIdx.x & 63;
    int node = blockIdx.x * 4 + (threadIdx.x >> 6);
    if (node >= N) return;
    float dn = dis[node];
    ushort2 sv = ((const ushort2*)(h + (size_t)node * 128))[lane];
    float2 acc = make_float2(b2f(sv.x), b2f(sv.y));
    int ne = min(fill[node], CAP);
    int pk = (lane < ne) ? stage[(node << 6) + lane] : 0;
    int j = 0;
    for (; j + 16 <= ne; j += 16) {
        ushort2 a[16];
#pragma unroll
        for (int t = 0; t < 16; t++) {
            int s = __builtin_amdgcn_readlane(pk, j + t);
            a[t] = ((const ushort2*)(h + (size_t)s * 128))[lane];
        }
#pragma unroll
        for (int t = 0; t < 16; t++) { acc.x += b2f(a[t].x); acc.y += b2f(a[t].y); }
    }
    for (; j + 8 <= ne; j += 8) {
        ushort2 a[8];
#pragma unroll
        for (int t = 0; t < 8; t++) {
            int s = __builtin_amdgcn_readlane(pk, j + t);
            a[t] = ((const ushort2*)(h + (size_t)s * 128))[lane];
        }
#pragma unroll
        for (int t = 0; t < 8; t++) { acc.x += b2f(a[t].x); acc.y += b2f(a[t].y); }
    }
    for (; j + 4 <= ne; j += 4) {
        ushort2 a[4];
#pragma unroll
        for (int t = 0; t < 4; t++) {
            int s = __builtin_amdgcn_readlane(pk, j + t);
            a[t] = ((const ushort2*)(h + (size_t)s * 128))[lane];
        }
#pragma unroll
        for (int t = 0; t < 4; t++) { acc.x += b2f(a[t].x); acc.y += b2f(a[t].y); }
    }
    for (; j < ne; j++) {
        int s = __builtin_amdgcn_readlane(pk, j);
        ushort2 a = ((const ushort2*)(h + (size_t)s * 128))[lane];
        acc.x += b2f(a.x);
        acc.y += b2f(a.y);
    }
    ((ushort2*)(out + (size_t)node * 128))[lane] =
        make_ushort2(f2bf(acc.x * dn), f2bf(acc.y * dn));
}

__global__ __launch_bounds__(256) void agg64_kernel(
    const unsigned short* __restrict__ h, const int* __restrict__ fill,
    const int* __restrict__ stage, const float* __restrict__ dis,
    unsigned short* __restrict__ out, int N) {
    int lane = threadIdx.x & 63;
    int node = blockIdx.x * 4 + (threadIdx.x >> 6);
    if (node >= N) return;
    int half = lane >> 5, ch = lane & 31;
    float dn = dis[node];
    float2 acc = make_float2(0.f, 0.f);
    if (half == 0) {
        ushort2 sv = ((const ushort2*)(h + (size_t)node * 64))[ch];
        acc.x = b2f(sv.x);
        acc.y = b2f(sv.y);
    }
    int ne = min(fill[node], CAP);
    int pk = (lane < ne) ? stage[(node << 6) + lane] : 0;
    int j = 0;
    for (; j + 16 <= ne; j += 16) {
        ushort2 a[8];
#pragma unroll
        for (int t = 0; t < 8; t++) {
            int s = __shfl(pk, j + 2 * t + half);
            a[t] = ((const ushort2*)(h + (size_t)s * 64))[ch];
        }
#pragma unroll
        for (int t = 0; t < 8; t++) { acc.x += b2f(a[t].x); acc.y += b2f(a[t].y); }
    }
    for (; j + 8 <= ne; j += 8) {
        ushort2 a[4];
#pragma unroll
        for (int t = 0; t < 4; t++) {
            int s = __shfl(pk, j + 2 * t + half);
            a[t] = ((const ushort2*)(h + (size_t)s * 64))[ch];
        }
#pragma unroll
        for (int t = 0; t < 4; t++) { acc.x += b2f(a[t].x); acc.y += b2f(a[t].y); }
    }
    for (; j < ne; j += 2) {
        int jj = j + half;
        int s = __shfl(pk, jj);
        bool v = jj < ne;
        ushort2 a = ((const ushort2*)(h + (size_t)s * 64))[ch];
        acc.x += v ? b2f(a.x) : 0.f;
        acc.y += v ? b2f(a.y) : 0.f;
    }
    acc.x += __shfl_down(acc.x, 32);
    acc.y += __shfl_down(acc.y, 32);
    if (half == 0)
        ((ushort2*)(out + (size_t)node * 64))[ch] =
            make_ushort2(f2bf(acc.x * dn), f2bf(acc.y * dn));
}

// ---------------- host -----------------------------------------------------

extern "C" void kernel_launch(void* const* d_in, const int* in_sizes, int n_in,
                              void* d_out, int out_size, void* d_ws, size_t ws_size,
                              hipStream_t stream) {
    const float* x = (const float*)d_in[0];
    const int* eidx = (const int*)d_in[1];
    const float* w0 = (const float*)d_in[2];
    const float* g0 = (const float*)d_in[4];
    const float* be0 = (const float*)d_in[5];
    const float* w1 = (const float*)d_in[6];
    const float* g1 = (const float*)d_in[8];
    const float* be1 = (const float*)d_in[9];
    const float* w2 = (const float*)d_in[10];
    const float* g2 = (const float*)d_in[12];
    const float* be2 = (const float*)d_in[13];
    const float* wc1 = (const float*)d_in[14];
    const float* bc1 = (const float*)d_in[15];
    const float* wc2 = (const float*)d_in[16];
    const float* bc2 = (const float*)d_in[17];
    float* outp = (float*)d_out;

    const int N = in_sizes[0] / 128;
    const int E = in_sizes[1] / 2;
    const int nbins = (N + BIN_NODES - 1) >> BIN_SHIFT;

    char* p = (char*)d_ws;
    auto alloc = [&](size_t bytes) {
        void* r = (void*)p;
        p += (bytes + 255) & ~(size_t)255;
        return r;
    };
    int* bin_fill = (int*)alloc((size_t)nbins * 4);
    int* fill = (int*)alloc((size_t)N * 4);
    int* binned = (int*)alloc((size_t)nbins * CAPB * 4);
    int* stage = (int*)alloc((size_t)N * CAP * 4);
    float* dis = (float*)alloc((size_t)N * 4);
    float* ss = (float*)alloc(3 * 256 * 4);
    float* partials = (float*)alloc((size_t)1024 * 256 * 4);  // stats partials / cntG
    unsigned short* hA = (unsigned short*)alloc((size_t)N * 128 * 2);
    unsigned short* hB = (unsigned short*)alloc((size_t)N * 128 * 2);
    unsigned short* wf = (unsigned short*)alloc(40960 * 2);
    unsigned short* wf1 = wf + 16384;
    unsigned short* wf2 = wf + 32768;

    float* sc0 = ss, *sh0 = ss + 128;
    float* sc1 = ss + 256, *sh1 = ss + 384;
    float* sc2 = ss + 512, *sh2 = ss + 640;
    int* cntG = (int*)partials;  // nbins*CB*4 <= 800KB <= 1MB

    // Cooperative residency: clamp grid to measured occupancy (deadlock safety).
    static int occA = 0, occB1 = 0, occB2 = 0, occC = 0;
    if (occA == 0) {
        hipOccupancyMaxActiveBlocksPerMultiprocessor(&occA, (const void*)fusedA_kernel, 256, 0);
        hipOccupancyMaxActiveBlocksPerMultiprocessor(&occB1, (const void*)fusedB_kernel<128, 128>, 256, 0);
        hipOccupancyMaxActiveBlocksPerMultiprocessor(&occB2, (const void*)fusedB_kernel<128, 64>, 256, 0);
        hipOccupancyMaxActiveBlocksPerMultiprocessor(&occC, (const void*)fusedC_kernel, 256, 0);
        if (occA < 1) occA = 1;
        if (occB1 < 1) occB1 = 1;
        if (occB2 < 1) occB2 = 1;
        if (occC < 1) occC = 1;
    }
    auto clampg = [](int occ) {
        int g = occ * 256;           // 256 CUs on gfx950
        return g > 1024 ? 1024 : g;  // partials buffer sized for <=1024 parts
    };
    int gA = clampg(occA), gB1 = clampg(occB1), gB2 = clampg(occB2), gC = clampg(occC);

    int CB = gA < 256 ? gA : 256;
    int chunk = (E + CB - 1) / CB;
    int Nv = N, Ev = E, nbv = nbins, CBv = CB, chv = chunk;

    {
        void* a[] = {(void*)&eidx, &Ev, &nbv, &CBv, &chv, &cntG, &bin_fill, &binned,
                     &Nv, &fill, &dis, &stage, (void*)&w0, (void*)&w1, (void*)&w2,
                     &wf, (void*)&x, &hA};
        hipLaunchCooperativeKernel((const void*)fusedA_kernel, dim3(gA), dim3(256), a, 0, stream);
    }
    int agg_grid = (N + 3) / 4;
    agg128_kernel<<<agg_grid, 256, 0, stream>>>(hA, fill, stage, dis, hB, N);
    {
        void* a[] = {&hB, (void*)&g0, (void*)&be0, &partials, &sc0, &sh0, &wf1, &dis, &hA, &Nv};
        hipLaunchCooperativeKernel((const void*)fusedB_kernel<128, 128>, dim3(gB1), dim3(256), a, 0, stream);
    }
    agg128_kernel<<<agg_grid, 256, 0, stream>>>(hA, fill, stage, dis, hB, N);
    {
        void* a[] = {&hB, (void*)&g1, (void*)&be1, &partials, &sc1, &sh1, &wf2, &dis, &hA, &Nv};
        hipLaunchCooperativeKernel((const void*)fusedB_kernel<128, 64>, dim3(gB2), dim3(256), a, 0, stream);
    }
    agg64_kernel<<<agg_grid, 256, 0, stream>>>(hA, fill, stage, dis, hB, N);
    {
        void* a[] = {&hB, (void*)&g2, (void*)&be2, &partials, &sc2, &sh2,
                     (void*)&wc1, (void*)&bc1, (void*)&wc2, (void*)&bc2, &outp, &Nv};
        hipLaunchCooperativeKernel((const void*)fusedC_kernel, dim3(gC), dim3(256), a, 0, stream);
    }
}

// Round 3
// 501.057 us; speedup vs baseline: 2.2381x; 2.2381x over previous
//
#include <hip/hip_runtime.h>

// ---------------------------------------------------------------------------
// GCN fraud detector — R13: de-dispatch without grid-wide sync.
// R12 post-mortem: cooperative grid.sync() on 8 non-coherent XCDs = device
//   fence + L2 writeback each time (VALUBusy 1%, 569us in fusedA). REVERTED.
// R13 changes vs R11 (436us):
//   * build: count/scan/place/part2 (4 dispatches) -> memset + ONE scatter
//     kernel with global atomicAdd(&fill[dst]) (1.6M ops over 100K addrs,
//     avg chain depth 16 — shallow; R10's lesson was 1024-deep chains).
//     stage[dst*64+p]=src directly; binned buffer gone; W-repack folded in.
//   * dis buffer gone — consumers compute rsqrtf(fill+1) inline.
//   * stats1 fused into agg kernels: grid-stride persistent agg (2048 blocks,
//     8/CU), per-thread register sum/sumsq (lane owns fixed channel pair),
//     one LDS cross-wave reduce at block end -> partials[2048][2C].
//     3 stats1 dispatches + 3x 25.6MB h re-reads removed.
//   17 dispatches -> 12.
// Agg gather loops: byte-identical to the proven 59.7us version (wave/node,
//   ushort2 rows, 16 gathers in flight; line-fill floor).
// ---------------------------------------------------------------------------

typedef __attribute__((ext_vector_type(8))) short short8;
typedef __attribute__((ext_vector_type(4))) float f32x4;

#define CAP 64
#define AGB 2048  // agg grid (persistent blocks) == stats partial count

__device__ __forceinline__ float b2f(unsigned short u) {
    return __uint_as_float(((unsigned)u) << 16);
}
__device__ __forceinline__ unsigned short f2bf(float f) {
    unsigned u = __float_as_uint(f);
    return (unsigned short)((u + 0x7fff + ((u >> 16) & 1)) >> 16);
}

// --- build: one pass. fill via global atomics; stage scatter; W repack fold ---
__global__ __launch_bounds__(256) void scatter_kernel(
    const int* __restrict__ eidx, int E, int N, int* __restrict__ fill,
    int* __restrict__ stage, const float* __restrict__ w0,
    const float* __restrict__ w1, const float* __restrict__ w2,
    unsigned short* __restrict__ wf) {
    int tg = blockIdx.x * 256 + threadIdx.x;
    if (tg < 40960) {  // folded W repack: fp32 -> bf16 B-fragment order
        const float* w;
        int idx, C;
        if (tg < 16384) { w = w0; idx = tg; C = 128; }
        else if (tg < 32768) { w = w1; idx = tg - 16384; C = 128; }
        else { w = w2; idx = tg - 32768; C = 64; }
        int j = idx & 7;
        int lane = (idx >> 3) & 63;
        int q = (idx >> 9) & 3;
        int n_tile = idx >> 11;
        int k = q * 32 + (lane >> 4) * 8 + j;
        int n = n_tile * 16 + (lane & 15);
        wf[tg] = f2bf(w[k * C + n]);
    }
    for (int e = tg; e < E; e += gridDim.x * 256) {
        int s = eidx[e];
        int d = eidx[E + e];
        int p = atomicAdd(&fill[d], 1);
        if (p < CAP) stage[(d << 6) + p] = s;
    }
}

__device__ __forceinline__ void load8(const float* p, float4& lo, float4& hi) {
    lo = *(const float4*)p;
    hi = *(const float4*)(p + 4);
}
__device__ __forceinline__ void load8(const unsigned short* p, float4& lo, float4& hi) {
    int4 q = *(const int4*)p;
    lo = make_float4(__uint_as_float((unsigned)q.x << 16),
                     __uint_as_float((unsigned)q.x & 0xffff0000u),
                     __uint_as_float((unsigned)q.y << 16),
                     __uint_as_float((unsigned)q.y & 0xffff0000u));
    hi = make_float4(__uint_as_float((unsigned)q.z << 16),
                     __uint_as_float((unsigned)q.z & 0xffff0000u),
                     __uint_as_float((unsigned)q.w << 16),
                     __uint_as_float((unsigned)q.w & 0xffff0000u));
}

// --- MFMA GEMM: out[N x C](bf16) = dis_row * (relu(xin*scale+shift) @ W) ---
template <int C, typename InT>
__global__ __launch_bounds__(256, 5) void mfma_gemm_kernel(
    const InT* __restrict__ xin, const unsigned short* __restrict__ wf,
    const float* __restrict__ scale, const float* __restrict__ shift,
    const int* __restrict__ fill, unsigned short* __restrict__ out, int N) {
    constexpr int NT = C / 16;
    constexpr int WFRAGS = NT * 4 * 64;
    __shared__ short8 ws[WFRAGS];
    int tid = threadIdx.x;
    for (int i = tid; i < WFRAGS; i += 256) ws[i] = ((const short8*)wf)[i];

    int lane = tid & 63;
    int wave = tid >> 6;
    int m0 = blockIdx.x * 64 + wave * 16;
    int r15 = lane & 15, r4 = lane >> 4;
    f32x4 acc[NT];
#pragma unroll
    for (int t = 0; t < NT; t++) acc[t] = (f32x4){0.f, 0.f, 0.f, 0.f};
    int row0c = min(m0 + r15, N - 1);
    __syncthreads();

#pragma unroll
    for (int q = 0; q < 4; q++) {
        int kb = q * 32 + r4 * 8;
        float4 a0l, a0h;
        load8(xin + (size_t)row0c * 128 + kb, a0l, a0h);
        if (scale) {
            float4 scl = *(const float4*)&scale[kb];
            float4 sch = *(const float4*)&scale[kb + 4];
            float4 shl = *(const float4*)&shift[kb];
            float4 shh = *(const float4*)&shift[kb + 4];
            a0l.x = fmaxf(a0l.x * scl.x + shl.x, 0.f);
            a0l.y = fmaxf(a0l.y * scl.y + shl.y, 0.f);
            a0l.z = fmaxf(a0l.z * scl.z + shl.z, 0.f);
            a0l.w = fmaxf(a0l.w * scl.w + shl.w, 0.f);
            a0h.x = fmaxf(a0h.x * sch.x + shh.x, 0.f);
            a0h.y = fmaxf(a0h.y * sch.y + shh.y, 0.f);
            a0h.z = fmaxf(a0h.z * sch.z + shh.z, 0.f);
            a0h.w = fmaxf(a0h.w * sch.w + shh.w, 0.f);
        }
        short8 a0;
        a0[0] = (short)f2bf(a0l.x); a0[1] = (short)f2bf(a0l.y);
        a0[2] = (short)f2bf(a0l.z); a0[3] = (short)f2bf(a0l.w);
        a0[4] = (short)f2bf(a0h.x); a0[5] = (short)f2bf(a0h.y);
        a0[6] = (short)f2bf(a0h.z); a0[7] = (short)f2bf(a0h.w);
#pragma unroll
        for (int nt = 0; nt < NT; nt++) {
            short8 b = ws[(nt * 4 + q) * 64 + lane];
            acc[nt] = __builtin_amdgcn_mfma_f32_16x16x32_bf16(a0, b, acc[nt], 0, 0, 0);
        }
    }
    float d0r[4];
#pragma unroll
    for (int r = 0; r < 4; r++) {
        int rowa = m0 + r4 * 4 + r;
        d0r[r] = (rowa < N) ? rsqrtf((float)fill[rowa] + 1.0f) : 0.f;
    }
#pragma unroll
    for (int nt = 0; nt < NT; nt++) {
        int col = nt * 16 + r15;
#pragma unroll
        for (int r = 0; r < 4; r++) {
            int rowa = m0 + r4 * 4 + r;
            if (rowa < N) out[(size_t)rowa * C + col] = f2bf(acc[nt][r] * d0r[r]);
        }
    }
}

// --- agg C=128 + fused BN-stats: persistent grid-stride, wave per node ---
__global__ __launch_bounds__(256) void agg128s_kernel(
    const unsigned short* __restrict__ h, const int* __restrict__ fill,
    const int* __restrict__ stage, unsigned short* __restrict__ out,
    float* __restrict__ partials, int N) {
    int lane = threadIdx.x & 63;
    int wave = threadIdx.x >> 6;
    int ngroups = (N + 3) >> 2;
    float2 s = make_float2(0.f, 0.f), qq = make_float2(0.f, 0.f);
    for (int g = blockIdx.x; g < ngroups; g += gridDim.x) {
        int node = g * 4 + wave;
        bool valid = node < N;
        int nodec = valid ? node : 0;
        float dn = rsqrtf((float)fill[nodec] + 1.0f);
        ushort2 sv = ((const ushort2*)(h + (size_t)nodec * 128))[lane];
        float2 acc = make_float2(b2f(sv.x), b2f(sv.y));
        int ne = valid ? min(fill[nodec], CAP) : 0;
        int pk = (lane < ne) ? stage[(nodec << 6) + lane] : 0;
        int j = 0;
        for (; j + 16 <= ne; j += 16) {
            ushort2 a[16];
#pragma unroll
            for (int t = 0; t < 16; t++) {
                int src = __builtin_amdgcn_readlane(pk, j + t);
                a[t] = ((const ushort2*)(h + (size_t)src * 128))[lane];
            }
#pragma unroll
            for (int t = 0; t < 16; t++) { acc.x += b2f(a[t].x); acc.y += b2f(a[t].y); }
        }
        for (; j + 8 <= ne; j += 8) {
            ushort2 a[8];
#pragma unroll
            for (int t = 0; t < 8; t++) {
                int src = __builtin_amdgcn_readlane(pk, j + t);
                a[t] = ((const ushort2*)(h + (size_t)src * 128))[lane];
            }
#pragma unroll
            for (int t = 0; t < 8; t++) { acc.x += b2f(a[t].x); acc.y += b2f(a[t].y); }
        }
        for (; j + 4 <= ne; j += 4) {
            ushort2 a[4];
#pragma unroll
            for (int t = 0; t < 4; t++) {
                int src = __builtin_amdgcn_readlane(pk, j + t);
                a[t] = ((const ushort2*)(h + (size_t)src * 128))[lane];
            }
#pragma unroll
            for (int t = 0; t < 4; t++) { acc.x += b2f(a[t].x); acc.y += b2f(a[t].y); }
        }
        for (; j < ne; j++) {
            int src = __builtin_amdgcn_readlane(pk, j);
            ushort2 a = ((const ushort2*)(h + (size_t)src * 128))[lane];
            acc.x += b2f(a.x);
            acc.y += b2f(a.y);
        }
        if (valid) {
            unsigned short rx = f2bf(acc.x * dn), ry = f2bf(acc.y * dn);
            ((ushort2*)(out + (size_t)node * 128))[lane] = make_ushort2(rx, ry);
            float fx = b2f(rx), fy = b2f(ry);
            s.x += fx; s.y += fy;
            qq.x += fx * fx; qq.y += fy * fy;
        }
    }
    // block reduce: channel ch=2*lane(+1); partials[blk][0..127]=sum,[128..255]=sumsq
    __shared__ float red[4][256];
    red[wave][2 * lane] = s.x;
    red[wave][2 * lane + 1] = s.y;
    red[wave][128 + 2 * lane] = qq.x;
    red[wave][128 + 2 * lane + 1] = qq.y;
    __syncthreads();
    int t = threadIdx.x;
    partials[(size_t)blockIdx.x * 256 + t] =
        red[0][t] + red[1][t] + red[2][t] + red[3][t];
}

// --- agg C=64 + fused BN-stats: wave per node, half-wave even/odd edges ---
__global__ __launch_bounds__(256) void agg64s_kernel(
    const unsigned short* __restrict__ h, const int* __restrict__ fill,
    const int* __restrict__ stage, unsigned short* __restrict__ out,
    float* __restrict__ partials, int N) {
    int lane = threadIdx.x & 63;
    int wave = threadIdx.x >> 6;
    int half = lane >> 5, ch = lane & 31;
    int ngroups = (N + 3) >> 2;
    float2 s = make_float2(0.f, 0.f), qq = make_float2(0.f, 0.f);
    for (int g = blockIdx.x; g < ngroups; g += gridDim.x) {
        int node = g * 4 + wave;
        bool valid = node < N;
        int nodec = valid ? node : 0;
        float dn = rsqrtf((float)fill[nodec] + 1.0f);
        float2 acc = make_float2(0.f, 0.f);
        if (half == 0) {
            ushort2 sv = ((const ushort2*)(h + (size_t)nodec * 64))[ch];
            acc.x = b2f(sv.x);
            acc.y = b2f(sv.y);
        }
        int ne = valid ? min(fill[nodec], CAP) : 0;
        int pk = (lane < ne) ? stage[(nodec << 6) + lane] : 0;
        int j = 0;
        for (; j + 16 <= ne; j += 16) {
            ushort2 a[8];
#pragma unroll
            for (int t = 0; t < 8; t++) {
                int src = __shfl(pk, j + 2 * t + half);
                a[t] = ((const ushort2*)(h + (size_t)src * 64))[ch];
            }
#pragma unroll
            for (int t = 0; t < 8; t++) { acc.x += b2f(a[t].x); acc.y += b2f(a[t].y); }
        }
        for (; j + 8 <= ne; j += 8) {
            ushort2 a[4];
#pragma unroll
            for (int t = 0; t < 4; t++) {
                int src = __shfl(pk, j + 2 * t + half);
                a[t] = ((const ushort2*)(h + (size_t)src * 64))[ch];
            }
#pragma unroll
            for (int t = 0; t < 4; t++) { acc.x += b2f(a[t].x); acc.y += b2f(a[t].y); }
        }
        for (; j < ne; j += 2) {
            int jj = j + half;
            int src = __shfl(pk, jj);
            bool v = jj < ne;
            ushort2 a = ((const ushort2*)(h + (size_t)src * 64))[ch];
            acc.x += v ? b2f(a.x) : 0.f;
            acc.y += v ? b2f(a.y) : 0.f;
        }
        acc.x += __shfl_down(acc.x, 32);
        acc.y += __shfl_down(acc.y, 32);
        if (valid && half == 0) {
            unsigned short rx = f2bf(acc.x * dn), ry = f2bf(acc.y * dn);
            ((ushort2*)(out + (size_t)node * 64))[ch] = make_ushort2(rx, ry);
            float fx = b2f(rx), fy = b2f(ry);
            s.x += fx; s.y += fy;
            qq.x += fx * fx; qq.y += fy * fy;
        }
    }
    // block reduce: half0 lanes own channels 2*ch(+1); [0..63]=sum,[64..127]=sumsq
    __shared__ float red[4][128];
    if (half == 0) {
        red[wave][2 * ch] = s.x;
        red[wave][2 * ch + 1] = s.y;
        red[wave][64 + 2 * ch] = qq.x;
        red[wave][64 + 2 * ch + 1] = qq.y;
    }
    __syncthreads();
    int t = threadIdx.x;
    if (t < 128)
        partials[(size_t)blockIdx.x * 128 + t] =
            red[0][t] + red[1][t] + red[2][t] + red[3][t];
}

// --- BN stats stage 2 (+finalize): block per channel, reduce AGB partials ---
template <int C>
__global__ __launch_bounds__(256) void stats2_kernel(const float* __restrict__ partials,
                                                     const float* __restrict__ g,
                                                     const float* __restrict__ be, int N,
                                                     int nparts, float* __restrict__ scale,
                                                     float* __restrict__ shift) {
    int c = blockIdx.x;
    int t = threadIdx.x;
    float s = 0.f, q = 0.f;
    for (int b = t; b < nparts; b += 256) {
        const float* pb = partials + (size_t)b * 2 * C;
        s += pb[c];
        q += pb[C + c];
    }
    __shared__ float rs[256], rq[256];
    rs[t] = s;
    rq[t] = q;
    __syncthreads();
    for (int d = 128; d > 0; d >>= 1) {
        if (t < d) {
            rs[t] += rs[t + d];
            rq[t] += rq[t + d];
        }
        __syncthreads();
    }
    if (t == 0) {
        float inv_n = 1.0f / (float)N;
        float mean = rs[0] * inv_n;
        float var = rq[0] * inv_n - mean * mean;
        var = var > 0.f ? var : 0.f;
        float sc = g[c] * rsqrtf(var + 1e-5f);
        scale[c] = sc;
        shift[c] = be[c] - mean * sc;
    }
}

__global__ __launch_bounds__(256) void head_kernel(
    const unsigned short* __restrict__ h, const float* __restrict__ scale,
    const float* __restrict__ shift, const float* __restrict__ wc1,
    const float* __restrict__ bc1, const float* __restrict__ wc2,
    const float* __restrict__ bc2, float* __restrict__ out, int N) {
    __shared__ float w1s[64 * 32];
    __shared__ float b1s[32], w2s[32], s2s[64], sh2[64];
    __shared__ float b2s;
    int tid = threadIdx.x;
    for (int i = tid; i < 64 * 32; i += 256) w1s[i] = wc1[i];
    if (tid < 32) { b1s[tid] = bc1[tid]; w2s[tid] = wc2[tid]; }
    if (tid < 64) { s2s[tid] = scale[tid]; sh2[tid] = shift[tid]; }
    if (tid == 0) b2s = bc2[0];
    __syncthreads();
    int n = blockIdx.x * 256 + tid;
    if (n >= N) return;
    float v[64];
#pragma unroll
    for (int k = 0; k < 64; k++) {
        float x = b2f(h[(size_t)n * 64 + k]) * s2s[k] + sh2[k];
        v[k] = x > 0.f ? x : 0.f;
    }
    float o = b2s;
#pragma unroll 2
    for (int j = 0; j < 32; j++) {
        float t = b1s[j];
#pragma unroll
        for (int k = 0; k < 64; k++) t += v[k] * w1s[k * 32 + j];
        t = t > 0.f ? t : 0.f;
        o += t * w2s[j];
    }
    out[n] = o;
}

extern "C" void kernel_launch(void* const* d_in, const int* in_sizes, int n_in,
                              void* d_out, int out_size, void* d_ws, size_t ws_size,
                              hipStream_t stream) {
    const float* x = (const float*)d_in[0];
    const int* eidx = (const int*)d_in[1];
    const float* w0 = (const float*)d_in[2];
    const float* g0 = (const float*)d_in[4];
    const float* be0 = (const float*)d_in[5];
    const float* w1 = (const float*)d_in[6];
    const float* g1 = (const float*)d_in[8];
    const float* be1 = (const float*)d_in[9];
    const float* w2 = (const float*)d_in[10];
    const float* g2 = (const float*)d_in[12];
    const float* be2 = (const float*)d_in[13];
    const float* wc1 = (const float*)d_in[14];
    const float* bc1 = (const float*)d_in[15];
    const float* wc2 = (const float*)d_in[16];
    const float* bc2 = (const float*)d_in[17];

    const int N = in_sizes[0] / 128;
    const int E = in_sizes[1] / 2;

    char* p = (char*)d_ws;
    auto alloc = [&](size_t bytes) {
        void* r = (void*)p;
        p += (bytes + 255) & ~(size_t)255;
        return r;
    };
    int* fill = (int*)alloc((size_t)N * 4);
    int* stage = (int*)alloc((size_t)N * CAP * 4);
    float* ss = (float*)alloc(3 * 256 * 4);
    float* partials = (float*)alloc((size_t)AGB * 256 * 4);
    unsigned short* hA = (unsigned short*)alloc((size_t)N * 128 * 2);
    unsigned short* hB = (unsigned short*)alloc((size_t)N * 128 * 2);
    unsigned short* wf = (unsigned short*)alloc(40960 * 2);
    unsigned short* wf0 = wf;
    unsigned short* wf1 = wf + 16384;
    unsigned short* wf2 = wf + 32768;

    float* sc0 = ss, *sh0 = ss + 128;
    float* sc1 = ss + 256, *sh1 = ss + 384;
    float* sc2 = ss + 512, *sh2 = ss + 640;

    hipMemsetAsync(fill, 0, (size_t)N * 4, stream);

    // --- build: one scatter pass (W repack folded) ---
    scatter_kernel<<<1024, 256, 0, stream>>>(eidx, E, N, fill, stage, w0, w1, w2, wf);

    int gemm_grid = (N + 63) / 64;

    // --- layer 0 ---
    mfma_gemm_kernel<128, float><<<gemm_grid, 256, 0, stream>>>(x, wf0, nullptr, nullptr,
                                                                fill, hA, N);
    agg128s_kernel<<<AGB, 256, 0, stream>>>(hA, fill, stage, hB, partials, N);
    stats2_kernel<128><<<128, 256, 0, stream>>>(partials, g0, be0, N, AGB, sc0, sh0);

    // --- layer 1 ---
    mfma_gemm_kernel<128, unsigned short><<<gemm_grid, 256, 0, stream>>>(
        hB, wf1, sc0, sh0, fill, hA, N);
    agg128s_kernel<<<AGB, 256, 0, stream>>>(hA, fill, stage, hB, partials, N);
    stats2_kernel<128><<<128, 256, 0, stream>>>(partials, g1, be1, N, AGB, sc1, sh1);

    // --- layer 2 (128 -> 64) ---
    mfma_gemm_kernel<64, unsigned short><<<gemm_grid, 256, 0, stream>>>(
        hB, wf2, sc1, sh1, fill, hA, N);
    agg64s_kernel<<<AGB, 256, 0, stream>>>(hA, fill, stage, hB, partials, N);
    stats2_kernel<64><<<64, 256, 0, stream>>>(partials, g2, be2, N, AGB, sc2, sh2);

    // --- head ---
    head_kernel<<<(N + 255) / 256, 256, 0, stream>>>(hB, sc2, sh2, wc1, bc1, wc2,
                                                     bc2, (float*)d_out, N);
}

// Round 4
// 423.807 us; speedup vs baseline: 2.6460x; 1.1823x over previous
//
#include <hip/hip_runtime.h>

// ---------------------------------------------------------------------------
// GCN fraud detector — R14: binned build (R11) + fused agg+stats (R13).
// R13 post-mortem: direct global scatter build = 140-148us. WRITE_SIZE 96MB
//   for 6.4MB payload -> random 4B scatters cost a full 64B line each
//   (write-allocate), plus uncoalesced atomic latency. The binned 2-phase
//   build keeps all scatter writes inside 32KB L2-resident bins (~25-30us).
//   REVERTED to R11 build. KEPT from R13: stats1 fused into agg kernels
//   (persistent 2048-block grid, register sum/sumsq, one LDS reduce/block;
//   saved ~55-60us vs separate stats1 passes), dis buffer dropped (inline
//   rsqrtf(fill+1)), W-repack folded into count kernel.
// R12 lesson: NO cooperative grid.sync on 8 non-coherent XCDs (O(100us)/sync).
// Agg gather loops: byte-identical to the proven 59.7us version (wave/node,
//   ushort2 rows, 16 gathers in flight; line-fill floor).
// 12 dispatches: count, scan, place, part2, 3x{gemm, agg+stats, stats2}, head.
// ---------------------------------------------------------------------------

typedef __attribute__((ext_vector_type(8))) short short8;
typedef __attribute__((ext_vector_type(4))) float f32x4;

#define BIN_SHIFT 7
#define BIN_NODES 128
#define CAPB 4096
#define CAP 64
#define AGB 2048  // agg grid (persistent blocks) == stats partial count
#define P1B 256   // graph-build blocks (== scan blockDim)

__device__ __forceinline__ float b2f(unsigned short u) {
    return __uint_as_float(((unsigned)u) << 16);
}
__device__ __forceinline__ unsigned short f2bf(float f) {
    unsigned u = __float_as_uint(f);
    return (unsigned short)((u + 0x7fff + ((u >> 16) & 1)) >> 16);
}

// --- build pass 1: per-block per-bin counts (no atomics) + W repack fold ---
__global__ __launch_bounds__(256) void count_kernel(
    const int* __restrict__ eidx, int E, int nbins, int chunk,
    int* __restrict__ cntG,
    const float* __restrict__ w0, const float* __restrict__ w1,
    const float* __restrict__ w2, unsigned short* __restrict__ wf) {
    __shared__ int cntS[1024];
    int tid = threadIdx.x;
    for (int b = tid; b < 1024; b += 256) cntS[b] = 0;

    // folded W repack: fp32 -> bf16 B-fragment order (40960 elems, blocks 0..159)
    int tg = blockIdx.x * 256 + tid;
    if (tg < 40960) {
        const float* w;
        int idx, C;
        if (tg < 16384) { w = w0; idx = tg; C = 128; }
        else if (tg < 32768) { w = w1; idx = tg - 16384; C = 128; }
        else { w = w2; idx = tg - 32768; C = 64; }
        int j = idx & 7;
        int lane = (idx >> 3) & 63;
        int q = (idx >> 9) & 3;
        int n_tile = idx >> 11;
        int k = q * 32 + (lane >> 4) * 8 + j;
        int n = n_tile * 16 + (lane & 15);
        wf[tg] = f2bf(w[k * C + n]);
    }
    __syncthreads();
    int e0 = blockIdx.x * chunk;
    int e1 = min(e0 + chunk, E);
    for (int e = e0 + tid; e < e1; e += 256)
        atomicAdd(&cntS[eidx[E + e] >> BIN_SHIFT], 1);
    __syncthreads();
    for (int b = tid; b < nbins; b += 256)
        cntG[b * P1B + blockIdx.x] = cntS[b];
}

// --- build pass 2: per-bin exclusive prefix over P1B block counts ---
__global__ __launch_bounds__(P1B) void scan_kernel(int* __restrict__ cntG,
                                                   int* __restrict__ bin_fill) {
    __shared__ int sh[P1B];
    int b = blockIdx.x, t = threadIdx.x;
    int v = cntG[b * P1B + t];
    sh[t] = v;
    __syncthreads();
    for (int d = 1; d < P1B; d <<= 1) {
        int u = (t >= d) ? sh[t - d] : 0;
        __syncthreads();
        sh[t] += u;
        __syncthreads();
    }
    cntG[b * P1B + t] = sh[t] - v;  // exclusive base, in place
    if (t == P1B - 1) bin_fill[b] = sh[P1B - 1];
}

// --- build pass 3: place edges, packed (src<<7 | dst&127), LDS atomics only ---
__global__ __launch_bounds__(256) void place_kernel(
    const int* __restrict__ eidx, int E, int nbins, int chunk,
    const int* __restrict__ baseG, int* __restrict__ binned) {
    __shared__ int cntS[1024];
    __shared__ int baseS[1024];
    int tid = threadIdx.x;
    for (int b = tid; b < nbins; b += 256) {
        baseS[b] = baseG[b * P1B + blockIdx.x];
        cntS[b] = 0;
    }
    __syncthreads();
    int e0 = blockIdx.x * chunk;
    int e1 = min(e0 + chunk, E);
    for (int e = e0 + tid; e < e1; e += 256) {
        int d = eidx[E + e];
        int s = eidx[e];
        int b = d >> BIN_SHIFT;
        int p = baseS[b] + atomicAdd(&cntS[b], 1);
        if (p < CAPB) binned[b * CAPB + p] = (s << BIN_SHIFT) | (d & (BIN_NODES - 1));
    }
}

// --- build pass 4: block per bin; LDS slot assignment; L2-local stage writes ---
__global__ __launch_bounds__(256) void part2_kernel(const int* __restrict__ bin_fill,
                                                    const int* __restrict__ binned,
                                                    int N, int* __restrict__ fill,
                                                    int* __restrict__ stage) {
    __shared__ int lfill[BIN_NODES];
    int b = blockIdx.x, tid = threadIdx.x;
    if (tid < BIN_NODES) lfill[tid] = 0;
    __syncthreads();
    int cnt = min(bin_fill[b], CAPB);
    const int* seg = binned + b * CAPB;
    for (int i = tid; i < cnt; i += 256) {
        int v = seg[i];
        int dl = v & (BIN_NODES - 1);
        int p = atomicAdd(&lfill[dl], 1);
        int node = (b << BIN_SHIFT) + dl;
        if (p < CAP) stage[(node << 6) + p] = v >> BIN_SHIFT;
    }
    __syncthreads();
    if (tid < BIN_NODES) {
        int node = (b << BIN_SHIFT) + tid;
        if (node < N) fill[node] = lfill[tid];
    }
}

__device__ __forceinline__ void load8(const float* p, float4& lo, float4& hi) {
    lo = *(const float4*)p;
    hi = *(const float4*)(p + 4);
}
__device__ __forceinline__ void load8(const unsigned short* p, float4& lo, float4& hi) {
    int4 q = *(const int4*)p;
    lo = make_float4(__uint_as_float((unsigned)q.x << 16),
                     __uint_as_float((unsigned)q.x & 0xffff0000u),
                     __uint_as_float((unsigned)q.y << 16),
                     __uint_as_float((unsigned)q.y & 0xffff0000u));
    hi = make_float4(__uint_as_float((unsigned)q.z << 16),
                     __uint_as_float((unsigned)q.z & 0xffff0000u),
                     __uint_as_float((unsigned)q.w << 16),
                     __uint_as_float((unsigned)q.w & 0xffff0000u));
}

// --- MFMA GEMM: out[N x C](bf16) = dis_row * (relu(xin*scale+shift) @ W) ---
template <int C, typename InT>
__global__ __launch_bounds__(256, 5) void mfma_gemm_kernel(
    const InT* __restrict__ xin, const unsigned short* __restrict__ wf,
    const float* __restrict__ scale, const float* __restrict__ shift,
    const int* __restrict__ fill, unsigned short* __restrict__ out, int N) {
    constexpr int NT = C / 16;
    constexpr int WFRAGS = NT * 4 * 64;
    __shared__ short8 ws[WFRAGS];
    int tid = threadIdx.x;
    for (int i = tid; i < WFRAGS; i += 256) ws[i] = ((const short8*)wf)[i];

    int lane = tid & 63;
    int wave = tid >> 6;
    int m0 = blockIdx.x * 64 + wave * 16;
    int r15 = lane & 15, r4 = lane >> 4;
    f32x4 acc[NT];
#pragma unroll
    for (int t = 0; t < NT; t++) acc[t] = (f32x4){0.f, 0.f, 0.f, 0.f};
    int row0c = min(m0 + r15, N - 1);
    __syncthreads();

#pragma unroll
    for (int q = 0; q < 4; q++) {
        int kb = q * 32 + r4 * 8;
        float4 a0l, a0h;
        load8(xin + (size_t)row0c * 128 + kb, a0l, a0h);
        if (scale) {
            float4 scl = *(const float4*)&scale[kb];
            float4 sch = *(const float4*)&scale[kb + 4];
            float4 shl = *(const float4*)&shift[kb];
            float4 shh = *(const float4*)&shift[kb + 4];
            a0l.x = fmaxf(a0l.x * scl.x + shl.x, 0.f);
            a0l.y = fmaxf(a0l.y * scl.y + shl.y, 0.f);
            a0l.z = fmaxf(a0l.z * scl.z + shl.z, 0.f);
            a0l.w = fmaxf(a0l.w * scl.w + shl.w, 0.f);
            a0h.x = fmaxf(a0h.x * sch.x + shh.x, 0.f);
            a0h.y = fmaxf(a0h.y * sch.y + shh.y, 0.f);
            a0h.z = fmaxf(a0h.z * sch.z + shh.z, 0.f);
            a0h.w = fmaxf(a0h.w * sch.w + shh.w, 0.f);
        }
        short8 a0;
        a0[0] = (short)f2bf(a0l.x); a0[1] = (short)f2bf(a0l.y);
        a0[2] = (short)f2bf(a0l.z); a0[3] = (short)f2bf(a0l.w);
        a0[4] = (short)f2bf(a0h.x); a0[5] = (short)f2bf(a0h.y);
        a0[6] = (short)f2bf(a0h.z); a0[7] = (short)f2bf(a0h.w);
#pragma unroll
        for (int nt = 0; nt < NT; nt++) {
            short8 b = ws[(nt * 4 + q) * 64 + lane];
            acc[nt] = __builtin_amdgcn_mfma_f32_16x16x32_bf16(a0, b, acc[nt], 0, 0, 0);
        }
    }
    float d0r[4];
#pragma unroll
    for (int r = 0; r < 4; r++) {
        int rowa = m0 + r4 * 4 + r;
        d0r[r] = (rowa < N) ? rsqrtf((float)fill[rowa] + 1.0f) : 0.f;
    }
#pragma unroll
    for (int nt = 0; nt < NT; nt++) {
        int col = nt * 16 + r15;
#pragma unroll
        for (int r = 0; r < 4; r++) {
            int rowa = m0 + r4 * 4 + r;
            if (rowa < N) out[(size_t)rowa * C + col] = f2bf(acc[nt][r] * d0r[r]);
        }
    }
}

// --- agg C=128 + fused BN-stats: persistent grid-stride, wave per node ---
__global__ __launch_bounds__(256) void agg128s_kernel(
    const unsigned short* __restrict__ h, const int* __restrict__ fill,
    const int* __restrict__ stage, unsigned short* __restrict__ out,
    float* __restrict__ partials, int N) {
    int lane = threadIdx.x & 63;
    int wave = threadIdx.x >> 6;
    int ngroups = (N + 3) >> 2;
    float2 s = make_float2(0.f, 0.f), qq = make_float2(0.f, 0.f);
    for (int g = blockIdx.x; g < ngroups; g += gridDim.x) {
        int node = g * 4 + wave;
        bool valid = node < N;
        int nodec = valid ? node : 0;
        float dn = rsqrtf((float)fill[nodec] + 1.0f);
        ushort2 sv = ((const ushort2*)(h + (size_t)nodec * 128))[lane];
        float2 acc = make_float2(b2f(sv.x), b2f(sv.y));
        int ne = valid ? min(fill[nodec], CAP) : 0;
        int pk = (lane < ne) ? stage[(nodec << 6) + lane] : 0;
        int j = 0;
        for (; j + 16 <= ne; j += 16) {
            ushort2 a[16];
#pragma unroll
            for (int t = 0; t < 16; t++) {
                int src = __builtin_amdgcn_readlane(pk, j + t);
                a[t] = ((const ushort2*)(h + (size_t)src * 128))[lane];
            }
#pragma unroll
            for (int t = 0; t < 16; t++) { acc.x += b2f(a[t].x); acc.y += b2f(a[t].y); }
        }
        for (; j + 8 <= ne; j += 8) {
            ushort2 a[8];
#pragma unroll
            for (int t = 0; t < 8; t++) {
                int src = __builtin_amdgcn_readlane(pk, j + t);
                a[t] = ((const ushort2*)(h + (size_t)src * 128))[lane];
            }
#pragma unroll
            for (int t = 0; t < 8; t++) { acc.x += b2f(a[t].x); acc.y += b2f(a[t].y); }
        }
        for (; j + 4 <= ne; j += 4) {
            ushort2 a[4];
#pragma unroll
            for (int t = 0; t < 4; t++) {
                int src = __builtin_amdgcn_readlane(pk, j + t);
                a[t] = ((const ushort2*)(h + (size_t)src * 128))[lane];
            }
#pragma unroll
            for (int t = 0; t < 4; t++) { acc.x += b2f(a[t].x); acc.y += b2f(a[t].y); }
        }
        for (; j < ne; j++) {
            int src = __builtin_amdgcn_readlane(pk, j);
            ushort2 a = ((const ushort2*)(h + (size_t)src * 128))[lane];
            acc.x += b2f(a.x);
            acc.y += b2f(a.y);
        }
        if (valid) {
            unsigned short rx = f2bf(acc.x * dn), ry = f2bf(acc.y * dn);
            ((ushort2*)(out + (size_t)node * 128))[lane] = make_ushort2(rx, ry);
            float fx = b2f(rx), fy = b2f(ry);
            s.x += fx; s.y += fy;
            qq.x += fx * fx; qq.y += fy * fy;
        }
    }
    // block reduce: channel ch=2*lane(+1); partials[blk][0..127]=sum,[128..255]=sumsq
    __shared__ float red[4][256];
    red[wave][2 * lane] = s.x;
    red[wave][2 * lane + 1] = s.y;
    red[wave][128 + 2 * lane] = qq.x;
    red[wave][128 + 2 * lane + 1] = qq.y;
    __syncthreads();
    int t = threadIdx.x;
    partials[(size_t)blockIdx.x * 256 + t] =
        red[0][t] + red[1][t] + red[2][t] + red[3][t];
}

// --- agg C=64 + fused BN-stats: wave per node, half-wave even/odd edges ---
__global__ __launch_bounds__(256) void agg64s_kernel(
    const unsigned short* __restrict__ h, const int* __restrict__ fill,
    const int* __restrict__ stage, unsigned short* __restrict__ out,
    float* __restrict__ partials, int N) {
    int lane = threadIdx.x & 63;
    int wave = threadIdx.x >> 6;
    int half = lane >> 5, ch = lane & 31;
    int ngroups = (N + 3) >> 2;
    float2 s = make_float2(0.f, 0.f), qq = make_float2(0.f, 0.f);
    for (int g = blockIdx.x; g < ngroups; g += gridDim.x) {
        int node = g * 4 + wave;
        bool valid = node < N;
        int nodec = valid ? node : 0;
        float dn = rsqrtf((float)fill[nodec] + 1.0f);
        float2 acc = make_float2(0.f, 0.f);
        if (half == 0) {
            ushort2 sv = ((const ushort2*)(h + (size_t)nodec * 64))[ch];
            acc.x = b2f(sv.x);
            acc.y = b2f(sv.y);
        }
        int ne = valid ? min(fill[nodec], CAP) : 0;
        int pk = (lane < ne) ? stage[(nodec << 6) + lane] : 0;
        int j = 0;
        for (; j + 16 <= ne; j += 16) {
            ushort2 a[8];
#pragma unroll
            for (int t = 0; t < 8; t++) {
                int src = __shfl(pk, j + 2 * t + half);
                a[t] = ((const ushort2*)(h + (size_t)src * 64))[ch];
            }
#pragma unroll
            for (int t = 0; t < 8; t++) { acc.x += b2f(a[t].x); acc.y += b2f(a[t].y); }
        }
        for (; j + 8 <= ne; j += 8) {
            ushort2 a[4];
#pragma unroll
            for (int t = 0; t < 4; t++) {
                int src = __shfl(pk, j + 2 * t + half);
                a[t] = ((const ushort2*)(h + (size_t)src * 64))[ch];
            }
#pragma unroll
            for (int t = 0; t < 4; t++) { acc.x += b2f(a[t].x); acc.y += b2f(a[t].y); }
        }
        for (; j < ne; j += 2) {
            int jj = j + half;
            int src = __shfl(pk, jj);
            bool v = jj < ne;
            ushort2 a = ((const ushort2*)(h + (size_t)src * 64))[ch];
            acc.x += v ? b2f(a.x) : 0.f;
            acc.y += v ? b2f(a.y) : 0.f;
        }
        acc.x += __shfl_down(acc.x, 32);
        acc.y += __shfl_down(acc.y, 32);
        if (valid && half == 0) {
            unsigned short rx = f2bf(acc.x * dn), ry = f2bf(acc.y * dn);
            ((ushort2*)(out + (size_t)node * 64))[ch] = make_ushort2(rx, ry);
            float fx = b2f(rx), fy = b2f(ry);
            s.x += fx; s.y += fy;
            qq.x += fx * fx; qq.y += fy * fy;
        }
    }
    // block reduce: half0 lanes own channels 2*ch(+1); [0..63]=sum,[64..127]=sumsq
    __shared__ float red[4][128];
    if (half == 0) {
        red[wave][2 * ch] = s.x;
        red[wave][2 * ch + 1] = s.y;
        red[wave][64 + 2 * ch] = qq.x;
        red[wave][64 + 2 * ch + 1] = qq.y;
    }
    __syncthreads();
    int t = threadIdx.x;
    if (t < 128)
        partials[(size_t)blockIdx.x * 128 + t] =
            red[0][t] + red[1][t] + red[2][t] + red[3][t];
}

// --- BN stats stage 2 (+finalize): block per channel, reduce AGB partials ---
template <int C>
__global__ __launch_bounds__(256) void stats2_kernel(const float* __restrict__ partials,
                                                     const float* __restrict__ g,
                                                     const float* __restrict__ be, int N,
                                                     int nparts, float* __restrict__ scale,
                                                     float* __restrict__ shift) {
    int c = blockIdx.x;
    int t = threadIdx.x;
    float s = 0.f, q = 0.f;
    for (int b = t; b < nparts; b += 256) {
        const float* pb = partials + (size_t)b * 2 * C;
        s += pb[c];
        q += pb[C + c];
    }
    __shared__ float rs[256], rq[256];
    rs[t] = s;
    rq[t] = q;
    __syncthreads();
    for (int d = 128; d > 0; d >>= 1) {
        if (t < d) {
            rs[t] += rs[t + d];
            rq[t] += rq[t + d];
        }
        __syncthreads();
    }
    if (t == 0) {
        float inv_n = 1.0f / (float)N;
        float mean = rs[0] * inv_n;
        float var = rq[0] * inv_n - mean * mean;
        var = var > 0.f ? var : 0.f;
        float sc = g[c] * rsqrtf(var + 1e-5f);
        scale[c] = sc;
        shift[c] = be[c] - mean * sc;
    }
}

__global__ __launch_bounds__(256) void head_kernel(
    const unsigned short* __restrict__ h, const float* __restrict__ scale,
    const float* __restrict__ shift, const float* __restrict__ wc1,
    const float* __restrict__ bc1, const float* __restrict__ wc2,
    const float* __restrict__ bc2, float* __restrict__ out, int N) {
    __shared__ float w1s[64 * 32];
    __shared__ float b1s[32], w2s[32], s2s[64], sh2[64];
    __shared__ float b2s;
    int tid = threadIdx.x;
    for (int i = tid; i < 64 * 32; i += 256) w1s[i] = wc1[i];
    if (tid < 32) { b1s[tid] = bc1[tid]; w2s[tid] = wc2[tid]; }
    if (tid < 64) { s2s[tid] = scale[tid]; sh2[tid] = shift[tid]; }
    if (tid == 0) b2s = bc2[0];
    __syncthreads();
    int n = blockIdx.x * 256 + tid;
    if (n >= N) return;
    float v[64];
#pragma unroll
    for (int k = 0; k < 64; k++) {
        float x = b2f(h[(size_t)n * 64 + k]) * s2s[k] + sh2[k];
        v[k] = x > 0.f ? x : 0.f;
    }
    float o = b2s;
#pragma unroll 2
    for (int j = 0; j < 32; j++) {
        float t = b1s[j];
#pragma unroll
        for (int k = 0; k < 64; k++) t += v[k] * w1s[k * 32 + j];
        t = t > 0.f ? t : 0.f;
        o += t * w2s[j];
    }
    out[n] = o;
}

extern "C" void kernel_launch(void* const* d_in, const int* in_sizes, int n_in,
                              void* d_out, int out_size, void* d_ws, size_t ws_size,
                              hipStream_t stream) {
    const float* x = (const float*)d_in[0];
    const int* eidx = (const int*)d_in[1];
    const float* w0 = (const float*)d_in[2];
    const float* g0 = (const float*)d_in[4];
    const float* be0 = (const float*)d_in[5];
    const float* w1 = (const float*)d_in[6];
    const float* g1 = (const float*)d_in[8];
    const float* be1 = (const float*)d_in[9];
    const float* w2 = (const float*)d_in[10];
    const float* g2 = (const float*)d_in[12];
    const float* be2 = (const float*)d_in[13];
    const float* wc1 = (const float*)d_in[14];
    const float* bc1 = (const float*)d_in[15];
    const float* wc2 = (const float*)d_in[16];
    const float* bc2 = (const float*)d_in[17];

    const int N = in_sizes[0] / 128;
    const int E = in_sizes[1] / 2;
    const int nbins = (N + BIN_NODES - 1) >> BIN_SHIFT;

    char* p = (char*)d_ws;
    auto alloc = [&](size_t bytes) {
        void* r = (void*)p;
        p += (bytes + 255) & ~(size_t)255;
        return r;
    };
    int* bin_fill = (int*)alloc((size_t)nbins * 4);
    int* fill = (int*)alloc((size_t)N * 4);
    int* binned = (int*)alloc((size_t)nbins * CAPB * 4);
    int* stage = (int*)alloc((size_t)N * CAP * 4);
    float* ss = (float*)alloc(3 * 256 * 4);
    float* partials = (float*)alloc((size_t)AGB * 256 * 4);
    unsigned short* hA = (unsigned short*)alloc((size_t)N * 128 * 2);
    unsigned short* hB = (unsigned short*)alloc((size_t)N * 128 * 2);
    unsigned short* wf = (unsigned short*)alloc(40960 * 2);
    unsigned short* wf0 = wf;
    unsigned short* wf1 = wf + 16384;
    unsigned short* wf2 = wf + 32768;

    float* sc0 = ss, *sh0 = ss + 128;
    float* sc1 = ss + 256, *sh1 = ss + 384;
    float* sc2 = ss + 512, *sh2 = ss + 640;

    // cntG/baseG reuse the partials buffer (nbins*P1B*4 = 800KB <= 2MB); the
    // graph build fully completes before the first agg writes partials.
    int* cntG = (int*)partials;

    // --- graph build: count -> scan -> place -> part2 (zero global atomics) ---
    int chunk = (E + P1B - 1) / P1B;
    count_kernel<<<P1B, 256, 0, stream>>>(eidx, E, nbins, chunk, cntG, w0, w1, w2, wf);
    scan_kernel<<<nbins, P1B, 0, stream>>>(cntG, bin_fill);
    place_kernel<<<P1B, 256, 0, stream>>>(eidx, E, nbins, chunk, cntG, binned);
    part2_kernel<<<nbins, 256, 0, stream>>>(bin_fill, binned, N, fill, stage);

    int gemm_grid = (N + 63) / 64;

    // --- layer 0 ---
    mfma_gemm_kernel<128, float><<<gemm_grid, 256, 0, stream>>>(x, wf0, nullptr, nullptr,
                                                                fill, hA, N);
    agg128s_kernel<<<AGB, 256, 0, stream>>>(hA, fill, stage, hB, partials, N);
    stats2_kernel<128><<<128, 256, 0, stream>>>(partials, g0, be0, N, AGB, sc0, sh0);

    // --- layer 1 ---
    mfma_gemm_kernel<128, unsigned short><<<gemm_grid, 256, 0, stream>>>(
        hB, wf1, sc0, sh0, fill, hA, N);
    agg128s_kernel<<<AGB, 256, 0, stream>>>(hA, fill, stage, hB, partials, N);
    stats2_kernel<128><<<128, 256, 0, stream>>>(partials, g1, be1, N, AGB, sc1, sh1);

    // --- layer 2 (128 -> 64) ---
    mfma_gemm_kernel<64, unsigned short><<<gemm_grid, 256, 0, stream>>>(
        hB, wf2, sc1, sh1, fill, hA, N);
    agg64s_kernel<<<AGB, 256, 0, stream>>>(hA, fill, stage, hB, partials, N);
    stats2_kernel<64><<<64, 256, 0, stream>>>(partials, g2, be2, N, AGB, sc2, sh2);

    // --- head ---
    head_kernel<<<(N + 255) / 256, 256, 0, stream>>>(hB, sc2, sh2, wc1, bc1, wc2,
                                                     bc2, (float*)d_out, N);
}